// Round 1
// baseline (2215.212 us; speedup 1.0000x reference)
//
#include <hip/hip_runtime.h>

typedef unsigned short u16;
typedef unsigned int u32;
typedef __attribute__((ext_vector_type(8))) short short8;
typedef __attribute__((ext_vector_type(4))) float f32x4;

// Problem constants
#define N_B 2
#define N_S 1024
#define N_DIN 2048
#define N_DOUT 2048
#define N_H 8
#define N_DK 64
#define N_DV 128
#define N_CONVD 2560
#define N_G 1024
#define N_NH 3584  // CONVD + G

__device__ __forceinline__ u16 f2bf(float f) {
  u32 u = __float_as_uint(f);
  u32 r = (u + 0x7FFFu + ((u >> 16) & 1u)) >> 16;
  return (u16)r;
}
__device__ __forceinline__ float bf2f(u16 s) { return __uint_as_float(((u32)s) << 16); }
__device__ __forceinline__ float fsigmoid(float x) {
  return __builtin_amdgcn_rcpf(1.f + __builtin_amdgcn_exp2f(-1.44269504f * x));
}

// ---------------- generic f32 -> bf16 convert ----------------
__global__ void cvt_kernel(const float* __restrict__ src, u16* __restrict__ dst, int n) {
  int i4 = (blockIdx.x * 256 + threadIdx.x) * 4;
  if (i4 + 3 < n) {
    float4 v = *(const float4*)&src[i4];
    dst[i4 + 0] = f2bf(v.x);
    dst[i4 + 1] = f2bf(v.y);
    dst[i4 + 2] = f2bf(v.z);
    dst[i4 + 3] = f2bf(v.w);
  }
}

// ---------------- W transpose: Wt[h][j][v] = W[h][v][j] (bf16) ----------------
__global__ void wtprep_kernel(const float* __restrict__ sw, u16* __restrict__ wtb) {
  int idx = blockIdx.x * 256 + threadIdx.x;  // h*16384 + j*128 + v
  if (idx >= N_H * 128 * 128) return;
  int h = idx >> 14;
  int rem = idx & 16383;
  int j = rem >> 7, v = rem & 127;
  wtb[idx] = f2bf(sw[((size_t)h * 128 + v) * 128 + j]);
}

// ---------------- bf16 NT GEMM: C[M][N] = A[M][K] * B[N][K]^T (+bias) ----------------
__global__ __launch_bounds__(256, 2) void gemm_bt(const u16* __restrict__ A,
                                                  const u16* __restrict__ B,
                                                  const float* __restrict__ bias,
                                                  float* __restrict__ C, int M, int N, int K) {
  const int tid = threadIdx.x;
  const int lane = tid & 63, w = tid >> 6;
  const int u = lane >> 4, m16 = lane & 15;
  const int wm = w & 1, wn = w >> 1;
  const int m0 = blockIdx.y * 128, n0 = blockIdx.x * 128;

  __shared__ __align__(16) u16 As[128 * 32];
  __shared__ __align__(16) u16 Bs[128 * 32];

  f32x4 acc[4][4];
#pragma unroll
  for (int i = 0; i < 4; ++i)
#pragma unroll
    for (int j = 0; j < 4; ++j)
#pragma unroll
      for (int r = 0; r < 4; ++r) acc[i][j][r] = 0.f;

  for (int kk = 0; kk < K; kk += 32) {
#pragma unroll
    for (int q = 0; q < 2; ++q) {
      int chunk = tid + 256 * q;
      int row = chunk >> 2, col = (chunk & 3) * 8;
      *(uint4*)&As[row * 32 + col] = *(const uint4*)&A[(size_t)(m0 + row) * K + kk + col];
      *(uint4*)&Bs[row * 32 + col] = *(const uint4*)&B[(size_t)(n0 + row) * K + kk + col];
    }
    __syncthreads();
    short8 af[4], bfr[4];
#pragma unroll
    for (int i = 0; i < 4; ++i) af[i] = *(const short8*)&As[(64 * wm + 16 * i + m16) * 32 + 8 * u];
#pragma unroll
    for (int i = 0; i < 4; ++i) bfr[i] = *(const short8*)&Bs[(64 * wn + 16 * i + m16) * 32 + 8 * u];
#pragma unroll
    for (int am = 0; am < 4; ++am)
#pragma unroll
      for (int bn = 0; bn < 4; ++bn)
        acc[am][bn] = __builtin_amdgcn_mfma_f32_16x16x32_bf16(af[am], bfr[bn], acc[am][bn], 0, 0, 0);
    __syncthreads();
  }
#pragma unroll
  for (int am = 0; am < 4; ++am)
#pragma unroll
    for (int bn = 0; bn < 4; ++bn) {
      int n = n0 + 64 * wn + 16 * bn + m16;
      float bv = bias ? bias[n] : 0.f;
#pragma unroll
      for (int r = 0; r < 4; ++r) {
        int m = m0 + 64 * wm + 16 * am + 4 * u + r;
        C[(size_t)m * N + n] = acc[am][bn][r] + bv;
      }
    }
}

// ---------------- depthwise causal conv (K=4) + SiLU + scatter to scan layout ----------------
// SCIN[b*8+h][t][320]: q[0,64) k[64,128) g/f[128,192) v[192,320)
__global__ void conv_kernel(const float* __restrict__ h, const float* __restrict__ cw,
                            const float* __restrict__ cb, float* __restrict__ SCIN) {
  int gid = blockIdx.x * 256 + threadIdx.x;
  if (gid >= N_B * N_S * N_CONVD) return;
  int c = gid % N_CONVD;
  int bt = gid / N_CONVD;
  int t = bt & 1023, b = bt >> 10;
  float4 wv = *(const float4*)&cw[c * 4];
  const float* wvp = (const float*)&wv;
  float acc = cb[c];
#pragma unroll
  for (int j = 0; j < 4; ++j) {
    int tt = t - 3 + j;
    if (tt >= 0) acc += wvp[j] * h[((size_t)(b * 1024 + tt)) * N_NH + c];
  }
  float yv = acc * fsigmoid(acc);  // silu
  int hh, off;
  if (c < 512) { hh = c >> 6; off = c & 63; }
  else if (c < 1024) { int cc = c - 512; hh = cc >> 6; off = 64 + (cc & 63); }
  else if (c < 2048) { int cc = c - 1024; hh = cc >> 7; off = 192 + (cc & 127); }
  else { int cc = c - 2048; hh = cc >> 6; off = 128 + (cc & 63); }
  SCIN[(((size_t)(b * 8 + hh)) * 1024 + t) * 320 + off] = yv;
}

// ---------------- k-normalize + forget-gate -> g (in place) ----------------
__global__ void prep2_kernel(float* __restrict__ SCIN, const float* __restrict__ fm,
                             const float* __restrict__ fb) {
  int widx = blockIdx.x * 4 + (threadIdx.x >> 6);  // one wave per (chain, t)
  int lane = threadIdx.x & 63;
  int chain = widx >> 10, t = widx & 1023;
  int hh = chain & 7;
  float* base = SCIN + ((size_t)chain * 1024 + t) * 320;
  float kv = base[64 + lane];
  float s = kv * kv;
#pragma unroll
  for (int m = 1; m < 64; m <<= 1) s += __shfl_xor(s, m, 64);
  float inv = __builtin_amdgcn_rsqf(s + 1e-12f);
  base[64 + lane] = kv * inv;
  float fv = base[128 + lane];
  float scale2 = 2.f * fsigmoid(fm[hh]);
  base[128 + lane] = fsigmoid(scale2 * (fv + fb[hh * 64 + lane]));
}

// ---------------- the sequential RSA scan: one workgroup per (b,h) chain ----------------
__global__ __launch_bounds__(256, 1) void scan_kernel(const u16* __restrict__ Wtb,
                                                      const float* __restrict__ SCIN,
                                                      float* __restrict__ Yb) {
  const int tid = threadIdx.x;
  const int lane = tid & 63, wv = tid >> 6;
  const int u = lane >> 4, m16 = lane & 15;
  const int i_lane = wv * 16 + m16;  // the dk row this lane owns (wave owns rows [16w,16w+16))
  const int chain = blockIdx.x;
  const int hh = chain & 7;

  __shared__ __align__(16) u16 Slds[64 * 136];      // S[i][v] bf16, row stride 136
  __shared__ __align__(16) float inbuf[2][320];     // double-buffered q,k,g,v
  __shared__ float ypart[2][128];
  __shared__ __align__(16) float ybuf[8 * 128];

  // W fragments resident in registers: A[m=j][k=v] = Wt[h][j][v]
  short8 Wfrag[8][4];
  {
    const u16* wb = Wtb + ((size_t)hh * 128 + m16) * 128 + 8 * u;
#pragma unroll
    for (int tj = 0; tj < 8; ++tj)
#pragma unroll
      for (int kc = 0; kc < 4; ++kc)
        Wfrag[tj][kc] = *(const short8*)(wb + tj * 16 * 128 + kc * 32);
  }

  for (int x = tid; x < 64 * 136; x += 256) Slds[x] = 0;

  const float* scin_c = SCIN + (size_t)chain * 1024 * 320;
  if (tid < 160) *(float2*)&inbuf[0][tid * 2] = *(const float2*)(scin_c + tid * 2);

  float Sreg[8][4];
#pragma unroll
  for (int a = 0; a < 8; ++a)
#pragma unroll
    for (int r = 0; r < 4; ++r) Sreg[a][r] = 0.f;

  __syncthreads();

  for (int t = 0; t < 1024; ++t) {
    const float* in = inbuf[t & 1];
    float2 pf;
    const bool dopf = (t < 1023) && (tid < 160);
    if (dopf) pf = *(const float2*)(scin_c + (size_t)(t + 1) * 320 + tid * 2);

    // X = Wt * S^T : D[j][i], each wave owns i-slice (n-tile = wave)
    short8 Bfrag[4];
#pragma unroll
    for (int kc = 0; kc < 4; ++kc)
      Bfrag[kc] = *(const short8*)&Slds[i_lane * 136 + 8 * u + 32 * kc];
    f32x4 acc[8];
#pragma unroll
    for (int tj = 0; tj < 8; ++tj) {
      acc[tj][0] = 0.f; acc[tj][1] = 0.f; acc[tj][2] = 0.f; acc[tj][3] = 0.f;
    }
#pragma unroll
    for (int kc = 0; kc < 4; ++kc)
#pragma unroll
      for (int tj = 0; tj < 8; ++tj)
        acc[tj] = __builtin_amdgcn_mfma_f32_16x16x32_bf16(Wfrag[tj][kc], Bfrag[kc], acc[tj], 0, 0, 0);

    const float gv = in[128 + i_lane];
    const float kv = in[64 + i_lane];

#pragma unroll
    for (int tj = 0; tj < 8; ++tj) {
      const int jb = 16 * tj + 4 * u;
      float4 vvec = *(const float4*)&in[192 + jb];
      const float* vvp = (const float*)&vvec;
#pragma unroll
      for (int r = 0; r < 4; ++r) {
        float arg = acc[tj][r] + vvp[r];
        float e = __builtin_amdgcn_exp2f(arg * 2.88539008f);          // e^{2x}
        float cand = 1.f - 2.f * __builtin_amdgcn_rcpf(e + 1.f);     // tanh(x)
        Sreg[tj][r] = gv * Sreg[tj][r] + kv * cand;
      }
      uint2 pck;
      pck.x = (u32)f2bf(Sreg[tj][0]) | ((u32)f2bf(Sreg[tj][1]) << 16);
      pck.y = (u32)f2bf(Sreg[tj][2]) | ((u32)f2bf(Sreg[tj][3]) << 16);
      *(uint2*)&Slds[i_lane * 136 + jb] = pck;  // wave-exclusive rows: race-free
    }

    if (dopf) *(float2*)&inbuf[(t + 1) & 1][tid * 2] = pf;
    __syncthreads();  // S_t visible; inbuf[t+1] ready

    // y_t[j] = sum_i q[i] * S_t[i][j]
    {
      const int j = tid & 127, half = tid >> 7;
      float p = 0.f;
#pragma unroll 8
      for (int ii = 0; ii < 32; ++ii) {
        const int i = half * 32 + ii;
        p += in[i] * bf2f(Slds[i * 136 + j]);
      }
      ypart[half][j] = p;
    }
    __syncthreads();
    if (tid < 128) ybuf[(t & 7) * 128 + tid] = ypart[0][tid] + ypart[1][tid];
    if ((t & 7) == 7) {
      __syncthreads();
      *(float4*)(Yb + ((size_t)chain * 1024 + (t - 7)) * 128 + tid * 4) =
          *(const float4*)&ybuf[tid * 4];
    }
  }
}

// ---------------- (y + v*D)*silu(gate), RMSNorm, *g_w -> bf16 ----------------
__global__ __launch_bounds__(256, 2) void post_kernel(const float* __restrict__ Yb,
                                                      const float* __restrict__ SCIN,
                                                      const float* __restrict__ h,
                                                      const float* __restrict__ Dp,
                                                      const float* __restrict__ gwv,
                                                      u16* __restrict__ Zb) {
  const int bt = blockIdx.x;
  const int b = bt >> 10, t = bt & 1023;
  const int lane = threadIdx.x & 63, wvi = threadIdx.x >> 6;
  float z[4];
  float ss = 0.f;
#pragma unroll
  for (int c = 0; c < 4; ++c) {
    int j = threadIdx.x + 256 * c;
    int head = j >> 7, dv = j & 127;
    int chain = b * 8 + head;
    float y = Yb[((size_t)chain * 1024 + t) * 128 + dv];
    float v = SCIN[((size_t)chain * 1024 + t) * 320 + 192 + dv];
    float gate = h[((size_t)(b * 1024 + t)) * N_NH + 2560 + j];
    float zz = (y + v * Dp[j]) * (gate * fsigmoid(gate));
    z[c] = zz;
    ss += zz * zz;
  }
#pragma unroll
  for (int m = 1; m < 64; m <<= 1) ss += __shfl_xor(ss, m, 64);
  __shared__ float red[4];
  if (lane == 0) red[wvi] = ss;
  __syncthreads();
  float tot = red[0] + red[1] + red[2] + red[3];
  float scale = __builtin_amdgcn_rsqf(tot * (1.f / 1024.f) + 1e-6f);
#pragma unroll
  for (int c = 0; c < 4; ++c) {
    int j = threadIdx.x + 256 * c;
    Zb[(size_t)(b * 1024 + t) * 1024 + j] = f2bf(z[c] * scale * gwv[j]);
  }
}

extern "C" void kernel_launch(void* const* d_in, const int* in_sizes, int n_in,
                              void* d_out, int out_size, void* d_ws, size_t ws_size,
                              hipStream_t stream) {
  const float* x    = (const float*)d_in[0];
  const float* w_in = (const float*)d_in[1];
  const float* b_in = (const float*)d_in[2];
  const float* cw   = (const float*)d_in[3];
  const float* cb   = (const float*)d_in[4];
  const float* Dp   = (const float*)d_in[5];
  const float* sw   = (const float*)d_in[6];
  const float* fm   = (const float*)d_in[7];
  const float* fb   = (const float*)d_in[8];
  const float* gwv  = (const float*)d_in[9];
  const float* wo   = (const float*)d_in[10];
  float* out = (float*)d_out;

  char* p = (char*)d_ws;
  auto alloc = [&](size_t bytes) {
    char* r = p;
    p += (bytes + 255) & ~(size_t)255;
    return r;
  };
  u16* xb    = (u16*)alloc((size_t)2048 * 2048 * 2);
  u16* wib   = (u16*)alloc((size_t)3584 * 2048 * 2);
  u16* wob   = (u16*)alloc((size_t)2048 * 1024 * 2);
  u16* wtb   = (u16*)alloc((size_t)8 * 128 * 128 * 2);
  float* hbf = (float*)alloc((size_t)2048 * 3584 * 4);
  float* scin= (float*)alloc((size_t)16 * 1024 * 320 * 4);
  float* yb  = (float*)alloc((size_t)16 * 1024 * 128 * 4);
  u16* zb    = (u16*)alloc((size_t)2048 * 1024 * 2);

  cvt_kernel<<<4096, 256, 0, stream>>>(x, xb, 2048 * 2048);
  cvt_kernel<<<7168, 256, 0, stream>>>(w_in, wib, 3584 * 2048);
  cvt_kernel<<<2048, 256, 0, stream>>>(wo, wob, 2048 * 1024);
  wtprep_kernel<<<512, 256, 0, stream>>>(sw, wtb);

  // h = x @ w_in^T + b_in
  gemm_bt<<<dim3(3584 / 128, 2048 / 128), 256, 0, stream>>>(xb, wib, b_in, hbf, 2048, 3584, 2048);

  conv_kernel<<<(N_B * N_S * N_CONVD) / 256, 256, 0, stream>>>(hbf, cw, cb, scin);
  prep2_kernel<<<(16 * 1024) / 4, 256, 0, stream>>>(scin, fm, fb);

  scan_kernel<<<16, 256, 0, stream>>>(wtb, scin, yb);

  post_kernel<<<2048, 256, 0, stream>>>(yb, scin, hbf, Dp, gwv, zb);

  // out = z @ w_out^T
  gemm_bt<<<dim3(2048 / 128, 2048 / 128), 256, 0, stream>>>(zb, wob, nullptr, out, 2048, 2048, 1024);
}

// Round 2
// 647.108 us; speedup vs baseline: 3.4232x; 3.4232x over previous
//
#include <hip/hip_runtime.h>

typedef unsigned short u16;
typedef unsigned int u32;
typedef __attribute__((ext_vector_type(8))) short short8;
typedef __attribute__((ext_vector_type(4))) float f32x4;

// Problem constants
#define N_B 2
#define N_S 1024
#define N_DIN 2048
#define N_DOUT 2048
#define N_H 8
#define N_DK 64
#define N_DV 128
#define N_CONVD 2560
#define N_G 1024
#define N_NH 3584  // CONVD + G

__device__ __forceinline__ u16 f2bf(float f) {
  u32 u = __float_as_uint(f);
  u32 r = (u + 0x7FFFu + ((u >> 16) & 1u)) >> 16;
  return (u16)r;
}
__device__ __forceinline__ float fsigmoid(float x) {
  return __builtin_amdgcn_rcpf(1.f + __builtin_amdgcn_exp2f(-1.44269504f * x));
}
// pack two f32 -> two bf16 (round-half-up) in one u32 via v_perm
__device__ __forceinline__ u32 pack_bf16_rhu(float a, float b) {
  u32 ua = __float_as_uint(a) + 0x8000u;
  u32 ub = __float_as_uint(b) + 0x8000u;
  return __builtin_amdgcn_perm(ub, ua, 0x07060302u);
}

// ---------------- generic f32 -> bf16 convert ----------------
__global__ void cvt_kernel(const float* __restrict__ src, u16* __restrict__ dst, int n) {
  int i4 = (blockIdx.x * 256 + threadIdx.x) * 4;
  if (i4 + 3 < n) {
    float4 v = *(const float4*)&src[i4];
    dst[i4 + 0] = f2bf(v.x);
    dst[i4 + 1] = f2bf(v.y);
    dst[i4 + 2] = f2bf(v.z);
    dst[i4 + 3] = f2bf(v.w);
  }
}

// ---------------- W transpose: Wt[h][j][v] = W[h][v][j] (bf16) ----------------
__global__ void wtprep_kernel(const float* __restrict__ sw, u16* __restrict__ wtb) {
  int idx = blockIdx.x * 256 + threadIdx.x;  // h*16384 + j*128 + v
  if (idx >= N_H * 128 * 128) return;
  int h = idx >> 14;
  int rem = idx & 16383;
  int j = rem >> 7, v = rem & 127;
  wtb[idx] = f2bf(sw[((size_t)h * 128 + v) * 128 + j]);
}

// ---------------- bf16 NT GEMM: C[M][N] = A[M][K] * B[N][K]^T (+bias) ----------------
__global__ __launch_bounds__(256, 2) void gemm_bt(const u16* __restrict__ A,
                                                  const u16* __restrict__ B,
                                                  const float* __restrict__ bias,
                                                  float* __restrict__ C, int M, int N, int K) {
  const int tid = threadIdx.x;
  const int lane = tid & 63, w = tid >> 6;
  const int u = lane >> 4, m16 = lane & 15;
  const int wm = w & 1, wn = w >> 1;
  const int m0 = blockIdx.y * 128, n0 = blockIdx.x * 128;

  __shared__ __align__(16) u16 As[128 * 32];
  __shared__ __align__(16) u16 Bs[128 * 32];

  f32x4 acc[4][4];
#pragma unroll
  for (int i = 0; i < 4; ++i)
#pragma unroll
    for (int j = 0; j < 4; ++j)
#pragma unroll
      for (int r = 0; r < 4; ++r) acc[i][j][r] = 0.f;

  for (int kk = 0; kk < K; kk += 32) {
#pragma unroll
    for (int q = 0; q < 2; ++q) {
      int chunk = tid + 256 * q;
      int row = chunk >> 2, col = (chunk & 3) * 8;
      *(uint4*)&As[row * 32 + col] = *(const uint4*)&A[(size_t)(m0 + row) * K + kk + col];
      *(uint4*)&Bs[row * 32 + col] = *(const uint4*)&B[(size_t)(n0 + row) * K + kk + col];
    }
    __syncthreads();
    short8 af[4], bfr[4];
#pragma unroll
    for (int i = 0; i < 4; ++i) af[i] = *(const short8*)&As[(64 * wm + 16 * i + m16) * 32 + 8 * u];
#pragma unroll
    for (int i = 0; i < 4; ++i) bfr[i] = *(const short8*)&Bs[(64 * wn + 16 * i + m16) * 32 + 8 * u];
#pragma unroll
    for (int am = 0; am < 4; ++am)
#pragma unroll
      for (int bn = 0; bn < 4; ++bn)
        acc[am][bn] = __builtin_amdgcn_mfma_f32_16x16x32_bf16(af[am], bfr[bn], acc[am][bn], 0, 0, 0);
    __syncthreads();
  }
#pragma unroll
  for (int am = 0; am < 4; ++am)
#pragma unroll
    for (int bn = 0; bn < 4; ++bn) {
      int n = n0 + 64 * wn + 16 * bn + m16;
      float bv = bias ? bias[n] : 0.f;
#pragma unroll
      for (int r = 0; r < 4; ++r) {
        int m = m0 + 64 * wm + 16 * am + 4 * u + r;
        C[(size_t)m * N + n] = acc[am][bn][r] + bv;
      }
    }
}

// ---------------- depthwise causal conv (K=4) + SiLU + scatter to scan layout ----------------
// SCIN[b*8+h][t][320]: q[0,64) k[64,128) g/f[128,192) v[192,320)
__global__ void conv_kernel(const float* __restrict__ h, const float* __restrict__ cw,
                            const float* __restrict__ cb, float* __restrict__ SCIN) {
  int gid = blockIdx.x * 256 + threadIdx.x;
  if (gid >= N_B * N_S * N_CONVD) return;
  int c = gid % N_CONVD;
  int bt = gid / N_CONVD;
  int t = bt & 1023, b = bt >> 10;
  float4 wv = *(const float4*)&cw[c * 4];
  const float* wvp = (const float*)&wv;
  float acc = cb[c];
#pragma unroll
  for (int j = 0; j < 4; ++j) {
    int tt = t - 3 + j;
    if (tt >= 0) acc += wvp[j] * h[((size_t)(b * 1024 + tt)) * N_NH + c];
  }
  float yv = acc * fsigmoid(acc);  // silu
  int hh, off;
  if (c < 512) { hh = c >> 6; off = c & 63; }
  else if (c < 1024) { int cc = c - 512; hh = cc >> 6; off = 64 + (cc & 63); }
  else if (c < 2048) { int cc = c - 1024; hh = cc >> 7; off = 192 + (cc & 127); }
  else { int cc = c - 2048; hh = cc >> 6; off = 128 + (cc & 63); }
  SCIN[(((size_t)(b * 8 + hh)) * 1024 + t) * 320 + off] = yv;
}

// ---------------- k-normalize + forget-gate -> g (in place) ----------------
__global__ void prep2_kernel(float* __restrict__ SCIN, const float* __restrict__ fm,
                             const float* __restrict__ fb) {
  int widx = blockIdx.x * 4 + (threadIdx.x >> 6);  // one wave per (chain, t)
  int lane = threadIdx.x & 63;
  int chain = widx >> 10, t = widx & 1023;
  int hh = chain & 7;
  float* base = SCIN + ((size_t)chain * 1024 + t) * 320;
  float kv = base[64 + lane];
  float s = kv * kv;
#pragma unroll
  for (int m = 1; m < 64; m <<= 1) s += __shfl_xor(s, m, 64);
  float inv = __builtin_amdgcn_rsqf(s + 1e-12f);
  base[64 + lane] = kv * inv;
  float fv = base[128 + lane];
  float scale2 = 2.f * fsigmoid(fm[hh]);
  base[128 + lane] = fsigmoid(scale2 * (fv + fb[hh * 64 + lane]));
}

// ---------------- the sequential RSA scan ----------------
// Grid: 64 WGs = 16 chains x 4 i-groups (16 dk-rows each). 512 threads = 8 waves.
// Wave wv owns j-columns [16wv,16wv+16); lane (u,m16) holds S[i=m16][j=16wv+4u+r] in f32.
// LDS holds a double-buffered bf16 copy of the WG's 16x128 S tile (B-operand for MFMA).
// Per step: X = Wt * S^T (MFMA), S = g*S + k*tanh(v + X), partial y = sum_i q[i]S[i][j]
// via DPP row-reduce -> global partials (summed in post_kernel).
__global__ __launch_bounds__(512, 2) void scan_kernel(const u16* __restrict__ Wtb,
                                                      const float* __restrict__ SCIN,
                                                      float* __restrict__ Ybp) {
  const int tid = threadIdx.x;
  const int lane = tid & 63, wv = tid >> 6;  // wv = tj (j-tile), 0..7
  const int u = lane >> 4, m16 = lane & 15;
  const int chain = blockIdx.x >> 2;
  const int ig = blockIdx.x & 3;  // dk row group: global i = 16*ig + m16
  const int hh = chain & 7;

  __shared__ __align__(16) u16 Slds[2][16 * 136];  // bf16 S tile, double-buffered

  // A-frag: A[m=m16][k=8u+idx] = Wt[hh][16wv+m16][32kc+8u+idx]
  short8 Wfrag[4];
  {
    const u16* wb = Wtb + ((size_t)hh * 128 + (16 * wv + m16)) * 128 + 8 * u;
#pragma unroll
    for (int kc = 0; kc < 4; ++kc) Wfrag[kc] = *(const short8*)(wb + 32 * kc);
  }

  for (int x = tid; x < 2 * 16 * 136; x += 512) ((u16*)Slds)[x] = 0;

  const float* scin_c = SCIN + (size_t)chain * 1024 * 320;
  float* ybase = Ybp + ((size_t)(chain * 4 + ig)) * 1024 * 128;

  float Sreg[4] = {0.f, 0.f, 0.f, 0.f};

  // t=0 inputs (registers, no LDS staging)
  float qv = scin_c[16 * ig + m16];
  float kv = scin_c[64 + 16 * ig + m16];
  float gv = scin_c[128 + 16 * ig + m16];
  float4 v4 = *(const float4*)&scin_c[192 + 16 * wv + 4 * u];

  __syncthreads();

  for (int t = 0; t < 1024; ++t) {
    // prefetch t+1 inputs into registers (stay in flight across the barrier)
    const int tn = (t + 1) & 1023;
    const float* pn = scin_c + (size_t)tn * 320;
    float qn = pn[16 * ig + m16];
    float kn = pn[64 + 16 * ig + m16];
    float gn = pn[128 + 16 * ig + m16];
    float4 vn = *(const float4*)&pn[192 + 16 * wv + 4 * u];

    const u16* Sr = Slds[t & 1];
    u16* Sw = Slds[(t + 1) & 1];

    // B-frag: B[k=8u+idx][n=m16] = S[m16][32kc+8u+idx]
    short8 Bfrag[4];
#pragma unroll
    for (int kc = 0; kc < 4; ++kc)
      Bfrag[kc] = *(const short8*)&Sr[m16 * 136 + 32 * kc + 8 * u];

    // X[j=16wv+4u+r][i=m16], two independent accumulator chains
    f32x4 acc0 = {0.f, 0.f, 0.f, 0.f}, acc1 = {0.f, 0.f, 0.f, 0.f};
    acc0 = __builtin_amdgcn_mfma_f32_16x16x32_bf16(Wfrag[0], Bfrag[0], acc0, 0, 0, 0);
    acc1 = __builtin_amdgcn_mfma_f32_16x16x32_bf16(Wfrag[1], Bfrag[1], acc1, 0, 0, 0);
    acc0 = __builtin_amdgcn_mfma_f32_16x16x32_bf16(Wfrag[2], Bfrag[2], acc0, 0, 0, 0);
    acc1 = __builtin_amdgcn_mfma_f32_16x16x32_bf16(Wfrag[3], Bfrag[3], acc1, 0, 0, 0);

    const float* vvp = (const float*)&v4;
    float p[4];
#pragma unroll
    for (int r = 0; r < 4; ++r) {
      float arg = (acc0[r] + acc1[r]) + vvp[r];
      float e = __builtin_amdgcn_exp2f(arg * 2.88539008f);       // e^{2x}
      float cand = 1.f - 2.f * __builtin_amdgcn_rcpf(e + 1.f);   // tanh(x)
      Sreg[r] = gv * Sreg[r] + kv * cand;
      p[r] = qv * Sreg[r];
    }

    // bf16 S tile for next step's B operand (wave-exclusive j-columns)
    uint2 pck;
    pck.x = pack_bf16_rhu(Sreg[0], Sreg[1]);
    pck.y = pack_bf16_rhu(Sreg[2], Sreg[3]);
    *(uint2*)&Sw[m16 * 136 + 16 * wv + 4 * u] = pck;

    // partial y over this WG's 16 rows: DPP prefix-reduce over m16; lane 15 holds sum
#pragma unroll
    for (int r = 0; r < 4; ++r) {
      float pr = p[r];
      pr += __int_as_float(__builtin_amdgcn_update_dpp(0, __float_as_int(pr), 0x111, 0xF, 0xF, true));
      pr += __int_as_float(__builtin_amdgcn_update_dpp(0, __float_as_int(pr), 0x112, 0xF, 0xF, true));
      pr += __int_as_float(__builtin_amdgcn_update_dpp(0, __float_as_int(pr), 0x114, 0xF, 0xF, true));
      pr += __int_as_float(__builtin_amdgcn_update_dpp(0, __float_as_int(pr), 0x118, 0xF, 0xF, true));
      p[r] = pr;
    }
    if (m16 == 15) {
      f32x4 yo;
      yo[0] = p[0]; yo[1] = p[1]; yo[2] = p[2]; yo[3] = p[3];
      *(f32x4*)(ybase + (size_t)t * 128 + 16 * wv + 4 * u) = yo;  // fire-and-forget
    }

    // LDS-only barrier: global stores/loads stay in flight (no vmcnt drain)
    asm volatile("s_waitcnt lgkmcnt(0)\n\ts_barrier" ::: "memory");

    qv = qn; kv = kn; gv = gn; v4 = vn;
  }
}

// ---------------- sum y partials, (y + v*D)*silu(gate), RMSNorm, *g_w -> bf16 ----------------
__global__ __launch_bounds__(256, 2) void post_kernel(const float* __restrict__ Ybp,
                                                      const float* __restrict__ SCIN,
                                                      const float* __restrict__ h,
                                                      const float* __restrict__ Dp,
                                                      const float* __restrict__ gwv,
                                                      u16* __restrict__ Zb) {
  const int bt = blockIdx.x;
  const int b = bt >> 10, t = bt & 1023;
  const int lane = threadIdx.x & 63, wvi = threadIdx.x >> 6;
  float z[4];
  float ss = 0.f;
#pragma unroll
  for (int c = 0; c < 4; ++c) {
    int j = threadIdx.x + 256 * c;
    int head = j >> 7, dv = j & 127;
    int chain = b * 8 + head;
    float y = 0.f;
#pragma unroll
    for (int igx = 0; igx < 4; ++igx)
      y += Ybp[(((size_t)(chain * 4 + igx)) * 1024 + t) * 128 + dv];
    float v = SCIN[((size_t)chain * 1024 + t) * 320 + 192 + dv];
    float gate = h[((size_t)(b * 1024 + t)) * N_NH + 2560 + j];
    float zz = (y + v * Dp[j]) * (gate * fsigmoid(gate));
    z[c] = zz;
    ss += zz * zz;
  }
#pragma unroll
  for (int m = 1; m < 64; m <<= 1) ss += __shfl_xor(ss, m, 64);
  __shared__ float red[4];
  if (lane == 0) red[wvi] = ss;
  __syncthreads();
  float tot = red[0] + red[1] + red[2] + red[3];
  float scale = __builtin_amdgcn_rsqf(tot * (1.f / 1024.f) + 1e-6f);
#pragma unroll
  for (int c = 0; c < 4; ++c) {
    int j = threadIdx.x + 256 * c;
    Zb[(size_t)(b * 1024 + t) * 1024 + j] = f2bf(z[c] * scale * gwv[j]);
  }
}

extern "C" void kernel_launch(void* const* d_in, const int* in_sizes, int n_in,
                              void* d_out, int out_size, void* d_ws, size_t ws_size,
                              hipStream_t stream) {
  const float* x    = (const float*)d_in[0];
  const float* w_in = (const float*)d_in[1];
  const float* b_in = (const float*)d_in[2];
  const float* cw   = (const float*)d_in[3];
  const float* cb   = (const float*)d_in[4];
  const float* Dp   = (const float*)d_in[5];
  const float* sw   = (const float*)d_in[6];
  const float* fm   = (const float*)d_in[7];
  const float* fb   = (const float*)d_in[8];
  const float* gwv  = (const float*)d_in[9];
  const float* wo   = (const float*)d_in[10];
  float* out = (float*)d_out;

  char* p = (char*)d_ws;
  auto alloc = [&](size_t bytes) {
    char* r = p;
    p += (bytes + 255) & ~(size_t)255;
    return r;
  };
  u16* xb    = (u16*)alloc((size_t)2048 * 2048 * 2);
  u16* wib   = (u16*)alloc((size_t)3584 * 2048 * 2);
  u16* wob   = (u16*)alloc((size_t)2048 * 1024 * 2);
  u16* wtb   = (u16*)alloc((size_t)8 * 128 * 128 * 2);
  float* hbf = (float*)alloc((size_t)2048 * 3584 * 4);
  float* scin= (float*)alloc((size_t)16 * 1024 * 320 * 4);
  float* ybp = (float*)alloc((size_t)64 * 1024 * 128 * 4);
  u16* zb    = (u16*)alloc((size_t)2048 * 1024 * 2);

  cvt_kernel<<<4096, 256, 0, stream>>>(x, xb, 2048 * 2048);
  cvt_kernel<<<7168, 256, 0, stream>>>(w_in, wib, 3584 * 2048);
  cvt_kernel<<<2048, 256, 0, stream>>>(wo, wob, 2048 * 1024);
  wtprep_kernel<<<512, 256, 0, stream>>>(sw, wtb);

  // h = x @ w_in^T + b_in
  gemm_bt<<<dim3(3584 / 128, 2048 / 128), 256, 0, stream>>>(xb, wib, b_in, hbf, 2048, 3584, 2048);

  conv_kernel<<<(N_B * N_S * N_CONVD) / 256, 256, 0, stream>>>(hbf, cw, cb, scin);
  prep2_kernel<<<(16 * 1024) / 4, 256, 0, stream>>>(scin, fm, fb);

  scan_kernel<<<64, 512, 0, stream>>>(wtb, scin, ybp);

  post_kernel<<<2048, 256, 0, stream>>>(ybp, scin, hbf, Dp, gwv, zb);

  // out = z @ w_out^T
  gemm_bt<<<dim3(2048 / 128, 2048 / 128), 256, 0, stream>>>(zb, wob, nullptr, out, 2048, 2048, 1024);
}